// Round 1
// baseline (359.693 us; speedup 1.0000x reference)
//
#include <hip/hip_runtime.h>
#include <stdint.h>

// Lovasz-Softmax loss, N=4M points, C=13 classes.
// Sort-free algorithm: per-class bucket histogram (B=1024) of errors; since
// Jaccard J(m,k) is monotone 0->1 in descending-error order and loss
// contribution within a bucket telescopes to mean_e * dJ, midpoint
// approximation has worst-case error <= 1/(2B) = 4.9e-4 << 1.84e-2 threshold.

#define NCLS 13
#define NB 1024              // buckets
#define ENTRIES (NCLS * NB)  // 13312
#define K1_BLOCK 512
#define K1_GRID 512

// K1: softmax + per-class error histogram in LDS, flush per-block to ws.
// LDS hist entry: (pos_count << 16) | total_count  (block handles < 8K pts)
__global__ __launch_bounds__(K1_BLOCK, 4)
void hist_kernel(const float* __restrict__ logits,
                 const int* __restrict__ targets,
                 uint32_t* __restrict__ partial, int ngroups) {
    __shared__ uint32_t hist[ENTRIES];
    for (int e = threadIdx.x; e < ENTRIES; e += K1_BLOCK) hist[e] = 0;
    __syncthreads();

    const float4* lp4 = reinterpret_cast<const float4*>(logits);
    const int4*   tg4 = reinterpret_cast<const int4*>(targets);
    int tid = blockIdx.x * K1_BLOCK + threadIdx.x;
    int nth = gridDim.x * K1_BLOCK;

    for (int g = tid; g < ngroups; g += nth) {
        // 4 points = 52 floats = 13 aligned float4 (208 B, 16B-aligned)
        float f[52];
        float4* fv = reinterpret_cast<float4*>(f);
        const float4* src = lp4 + (size_t)g * 13;
        #pragma unroll
        for (int j = 0; j < 13; ++j) fv[j] = src[j];
        int4 tg = tg4[g];
        int tgt[4] = {tg.x, tg.y, tg.z, tg.w};

        #pragma unroll
        for (int q = 0; q < 4; ++q) {
            float m = f[13*q];
            #pragma unroll
            for (int c = 1; c < 13; ++c) m = fmaxf(m, f[13*q + c]);
            float s = 0.f;
            #pragma unroll
            for (int c = 0; c < 13; ++c) {
                float ex = __expf(f[13*q + c] - m);
                f[13*q + c] = ex;
                s += ex;
            }
            float inv = 1.f / s;
            int t = tgt[q];
            #pragma unroll
            for (int c = 0; c < 13; ++c) {
                float p = f[13*q + c] * inv;
                bool pos = (c == t);
                float e = pos ? (1.f - p) : p;
                int b = (int)(e * (float)NB);
                b = b > NB - 1 ? NB - 1 : b;
                atomicAdd(&hist[c * NB + b], pos ? 0x10001u : 1u);
            }
        }
    }
    __syncthreads();
    uint32_t* out = partial + (size_t)blockIdx.x * ENTRIES;
    for (int e = threadIdx.x; e < ENTRIES; e += K1_BLOCK) out[e] = hist[e];
}

// K2a: reduce 512 per-block histograms -> 8 partials per entry (u64: pos<<32|cnt)
__global__ void reduce_kernel(const uint32_t* __restrict__ partial,
                              uint64_t* __restrict__ p2) {
    int e = blockIdx.x * 256 + threadIdx.x;  // 52*256 = 13312 exact
    int j = blockIdx.y;                      // 0..7, each sums 64 blocks
    uint32_t cnt = 0, pos = 0;
    const uint32_t* base = partial + (size_t)j * 64 * ENTRIES + e;
    #pragma unroll 4
    for (int b = 0; b < 64; ++b) {
        uint32_t v = base[(size_t)b * ENTRIES];
        cnt += v & 0xFFFFu;
        pos += v >> 16;
    }
    p2[(size_t)j * ENTRIES + e] = ((uint64_t)pos << 32) | cnt;
}

// K2b: one block, 13 waves; per-class descending bucket scan -> loss.
__global__ void loss_kernel(const uint64_t* __restrict__ p2,
                            float* __restrict__ out) {
    __shared__ float ls[NCLS];
    int wave = threadIdx.x >> 6;
    int lane = threadIdx.x & 63;
    if (wave < NCLS) {
        int c = wave;
        uint32_t cnt_a[NB / 64], pos_a[NB / 64];
        int lanePos = 0;
        #pragma unroll
        for (int ch = 0; ch < NB / 64; ++ch) {
            int b = NB - 1 - (ch * 64 + lane);  // descending error order
            int e = c * NB + b;
            uint32_t cnt = 0, pos = 0;
            #pragma unroll
            for (int j = 0; j < 8; ++j) {
                uint64_t v = p2[(size_t)j * ENTRIES + e];
                cnt += (uint32_t)v;
                pos += (uint32_t)(v >> 32);
            }
            cnt_a[ch] = cnt;
            pos_a[ch] = pos;
            lanePos += (int)pos;
        }
        int Ptot = lanePos;
        #pragma unroll
        for (int d = 32; d > 0; d >>= 1) Ptot += __shfl_xor(Ptot, d);

        double acc = 0.0;
        unsigned Mc = 0, Kc = 0;  // cumulative count / positives (uniform)
        #pragma unroll
        for (int ch = 0; ch < NB / 64; ++ch) {
            unsigned pc = cnt_a[ch], pp = pos_a[ch];
            // inclusive prefix sum over lanes (= descending bucket order)
            #pragma unroll
            for (int d = 1; d < 64; d <<= 1) {
                unsigned tc = __shfl_up(pc, d);
                unsigned tp = __shfl_up(pp, d);
                if (lane >= d) { pc += tc; pp += tp; }
            }
            unsigned M  = Mc + pc,          K  = Kc + pp;
            unsigned Mp = M - cnt_a[ch],    Kp = K - pos_a[ch];
            double J1, J0;
            if (Ptot > 0) {
                J1 = 1.0 - (double)(Ptot - (int)K)  / (double)(Ptot + (int)M  - (int)K);
                J0 = 1.0 - (double)(Ptot - (int)Kp) / (double)(Ptot + (int)Mp - (int)Kp);
            } else {
                J1 = (M  > 0) ? 1.0 : 0.0;
                J0 = (Mp > 0) ? 1.0 : 0.0;
            }
            int b = NB - 1 - (ch * 64 + lane);
            double emid = ((double)b + 0.5) / (double)NB;
            acc += emid * (J1 - J0);
            Mc += __shfl(pc, 63);
            Kc += __shfl(pp, 63);
        }
        #pragma unroll
        for (int d = 32; d > 0; d >>= 1) acc += __shfl_xor(acc, d);
        if (lane == 0) ls[c] = (float)acc;
    }
    __syncthreads();
    if (threadIdx.x == 0) {
        float s = 0.f;
        for (int c = 0; c < NCLS; ++c) s += ls[c];
        out[0] = s / (float)NCLS;
    }
}

extern "C" void kernel_launch(void* const* d_in, const int* in_sizes, int n_in,
                              void* d_out, int out_size, void* d_ws, size_t ws_size,
                              hipStream_t stream) {
    const float* logits  = (const float*)d_in[0];
    const int*   targets = (const int*)d_in[1];
    int N = in_sizes[1];        // 4,000,000 (divisible by 4)
    int ngroups = N / 4;

    uint32_t* partial = (uint32_t*)d_ws;                                   // 512*13312*4 = 27.3 MB
    uint64_t* p2 = (uint64_t*)((char*)d_ws + (size_t)K1_GRID * ENTRIES * 4); // 8*13312*8 = 0.85 MB

    hist_kernel<<<K1_GRID, K1_BLOCK, 0, stream>>>(logits, targets, partial, ngroups);
    reduce_kernel<<<dim3(ENTRIES / 256, 8), 256, 0, stream>>>(partial, p2);
    loss_kernel<<<1, 832, 0, stream>>>(p2, (float*)d_out);
}

// Round 2
// 311.757 us; speedup vs baseline: 1.1538x; 1.1538x over previous
//
#include <hip/hip_runtime.h>
#include <stdint.h>

// Lovasz-Softmax loss, N=4M, C=13. Sort-free bucket-histogram algorithm:
// Jaccard is monotone in descending-error order, so per-class loss =
// sum over buckets of mean_err * dJ; midpoint approx error <= 1/(2*NB).
// NB=256 -> worst case 2.0e-3 per class, threshold is 1.84e-2.

#define NCLS 13
#define NB 256
#define ENTRIES (NCLS * NB)          // 3328
#define K1_BLOCK 256
#define K1_GRID 2048
#define RED_J 16
#define BLK_PER_J (K1_GRID / RED_J)  // 128

// K1: one point per thread; softmax; LDS histogram (pos<<16|cnt packed,
// per-block increments <= 26.6K < 65535 so u16 fields are safe).
__global__ __launch_bounds__(K1_BLOCK, 8)
void hist_kernel(const float* __restrict__ logits,
                 const int* __restrict__ targets,
                 uint32_t* __restrict__ partial, int npts) {
    __shared__ uint32_t hist[ENTRIES];
    for (int e = threadIdx.x; e < ENTRIES; e += K1_BLOCK) hist[e] = 0;
    __syncthreads();

    int tid = blockIdx.x * K1_BLOCK + threadIdx.x;
    int nth = K1_GRID * K1_BLOCK;

    for (int p = tid; p < npts; p += nth) {
        const float* row = logits + (size_t)p * NCLS;
        float v[NCLS];
        #pragma unroll
        for (int c = 0; c < NCLS; ++c) v[c] = row[c];   // 52B/lane stride: wave span 3.3KB, L1-resident
        int t = targets[p];
        float m = v[0];
        #pragma unroll
        for (int c = 1; c < NCLS; ++c) m = fmaxf(m, v[c]);
        float s = 0.f;
        #pragma unroll
        for (int c = 0; c < NCLS; ++c) { v[c] = __expf(v[c] - m); s += v[c]; }
        float inv = 1.f / s;
        #pragma unroll
        for (int c = 0; c < NCLS; ++c) {
            float prob = v[c] * inv;
            bool pos = (c == t);
            float e = pos ? (1.f - prob) : prob;
            int b = (int)(e * (float)NB);
            b = b > NB - 1 ? NB - 1 : b;
            atomicAdd(&hist[c * NB + b], pos ? 0x10001u : 1u);
        }
    }
    __syncthreads();
    uint32_t* outp = partial + (size_t)blockIdx.x * ENTRIES;
    for (int e = threadIdx.x; e < ENTRIES; e += K1_BLOCK) outp[e] = hist[e];
}

// K2a: reduce 2048 per-block histograms -> 16 partials/entry (u64 pos<<32|cnt)
__global__ void reduce_kernel(const uint32_t* __restrict__ partial,
                              uint64_t* __restrict__ p2) {
    int e = blockIdx.x * 256 + threadIdx.x;   // 13 * 256 = 3328 exact
    int j = blockIdx.y;                       // 0..15, each sums 128 blocks
    uint32_t cnt = 0, pos = 0;
    const uint32_t* base = partial + (size_t)j * BLK_PER_J * ENTRIES + e;
    #pragma unroll 8
    for (int b = 0; b < BLK_PER_J; ++b) {
        uint32_t v = base[(size_t)b * ENTRIES];
        cnt += v & 0xFFFFu;
        pos += v >> 16;
    }
    p2[(size_t)j * ENTRIES + e] = ((uint64_t)pos << 32) | cnt;
}

// K2b: one block, 13 waves; per-class descending bucket scan -> loss.
__global__ void loss_kernel(const uint64_t* __restrict__ p2,
                            float* __restrict__ out) {
    __shared__ float ls[NCLS];
    int wave = threadIdx.x >> 6;
    int lane = threadIdx.x & 63;
    if (wave < NCLS) {
        int c = wave;
        uint32_t cnt_a[NB / 64], pos_a[NB / 64];
        int lanePos = 0;
        #pragma unroll
        for (int ch = 0; ch < NB / 64; ++ch) {
            int b = NB - 1 - (ch * 64 + lane);  // descending error order
            int e = c * NB + b;
            uint32_t cnt = 0, pos = 0;
            #pragma unroll
            for (int j = 0; j < RED_J; ++j) {
                uint64_t v = p2[(size_t)j * ENTRIES + e];
                cnt += (uint32_t)v;
                pos += (uint32_t)(v >> 32);
            }
            cnt_a[ch] = cnt;
            pos_a[ch] = pos;
            lanePos += (int)pos;
        }
        int Ptot = lanePos;
        #pragma unroll
        for (int d = 32; d > 0; d >>= 1) Ptot += __shfl_xor(Ptot, d);

        double acc = 0.0;
        unsigned Mc = 0, Kc = 0;
        #pragma unroll
        for (int ch = 0; ch < NB / 64; ++ch) {
            unsigned pc = cnt_a[ch], pp = pos_a[ch];
            #pragma unroll
            for (int d = 1; d < 64; d <<= 1) {  // inclusive lane prefix sum
                unsigned tc = __shfl_up(pc, d);
                unsigned tp = __shfl_up(pp, d);
                if (lane >= d) { pc += tc; pp += tp; }
            }
            unsigned M  = Mc + pc,        K  = Kc + pp;
            unsigned Mp = M - cnt_a[ch],  Kp = K - pos_a[ch];
            double J1, J0;
            if (Ptot > 0) {
                J1 = 1.0 - (double)(Ptot - (int)K)  / (double)(Ptot + (int)M  - (int)K);
                J0 = 1.0 - (double)(Ptot - (int)Kp) / (double)(Ptot + (int)Mp - (int)Kp);
            } else {
                J1 = (M  > 0) ? 1.0 : 0.0;
                J0 = (Mp > 0) ? 1.0 : 0.0;
            }
            int b = NB - 1 - (ch * 64 + lane);
            double emid = ((double)b + 0.5) / (double)NB;
            acc += emid * (J1 - J0);
            Mc += __shfl(pc, 63);
            Kc += __shfl(pp, 63);
        }
        #pragma unroll
        for (int d = 32; d > 0; d >>= 1) acc += __shfl_xor(acc, d);
        if (lane == 0) ls[c] = (float)acc;
    }
    __syncthreads();
    if (threadIdx.x == 0) {
        float s = 0.f;
        for (int c = 0; c < NCLS; ++c) s += ls[c];
        out[0] = s / (float)NCLS;
    }
}

extern "C" void kernel_launch(void* const* d_in, const int* in_sizes, int n_in,
                              void* d_out, int out_size, void* d_ws, size_t ws_size,
                              hipStream_t stream) {
    const float* logits  = (const float*)d_in[0];
    const int*   targets = (const int*)d_in[1];
    int N = in_sizes[1];  // 4,000,000

    uint32_t* partial = (uint32_t*)d_ws;                         // 2048*3328*4 = 27.3 MB
    uint64_t* p2 = (uint64_t*)((char*)d_ws +
                   (size_t)K1_GRID * ENTRIES * sizeof(uint32_t)); // 16*3328*8 = 426 KB

    hist_kernel<<<K1_GRID, K1_BLOCK, 0, stream>>>(logits, targets, partial, N);
    reduce_kernel<<<dim3(ENTRIES / 256, RED_J), 256, 0, stream>>>(partial, p2);
    loss_kernel<<<1, 832, 0, stream>>>(p2, (float*)d_out);
}